// Round 1
// baseline (332.875 us; speedup 1.0000x reference)
//
#include <hip/hip_runtime.h>
#include <math.h>

#define BB 256
#define LL 500
#define EE 300
#define NROWS (BB * LL)      // 128000
#define NJ 18                // 3 (aw3) + 1 (cw3) + 5 (aw5) + 1 (cw5) + 7 (aw7) + 1 (cw7)
#define E4 (EE / 4)          // 75 float4 per row

// ---------------------------------------------------------------------------
// Phase 1: for each row r = b*L + l, compute 18 dot products of x[r,:] (E=300)
// with: aw3[0..2], cw3, aw5[0..4], cw5, aw7[0..6], cw7.
// Stored transposed: dots[j*NROWS + r]  (coalesced store + coalesced phase-2 read).
// Weight addresses depend only on loop counters -> wave-uniform -> scalar loads.
// ---------------------------------------------------------------------------
__global__ __launch_bounds__(256) void dots_kernel(
    const float* __restrict__ x,
    const float* __restrict__ aw3, const float* __restrict__ cw3,
    const float* __restrict__ aw5, const float* __restrict__ cw5,
    const float* __restrict__ aw7, const float* __restrict__ cw7,
    float* __restrict__ dots)
{
    const int r = blockIdx.x * blockDim.x + threadIdx.x;
    if (r >= NROWS) return;

    const float4* __restrict__ xr = (const float4*)(x + (size_t)r * EE);
    const float4* __restrict__ a3 = (const float4*)aw3;
    const float4* __restrict__ c3 = (const float4*)cw3;
    const float4* __restrict__ a5 = (const float4*)aw5;
    const float4* __restrict__ c5 = (const float4*)cw5;
    const float4* __restrict__ a7 = (const float4*)aw7;
    const float4* __restrict__ c7 = (const float4*)cw7;

    float acc[NJ];
#pragma unroll
    for (int j = 0; j < NJ; ++j) acc[j] = 0.0f;

#pragma unroll 5
    for (int i = 0; i < E4; ++i) {
        const float4 xv = xr[i];

#pragma unroll
        for (int t = 0; t < 3; ++t) {
            const float4 w = a3[t * E4 + i];
            acc[t] += xv.x * w.x + xv.y * w.y + xv.z * w.z + xv.w * w.w;
        }
        {
            const float4 w = c3[i];
            acc[3] += xv.x * w.x + xv.y * w.y + xv.z * w.z + xv.w * w.w;
        }
#pragma unroll
        for (int t = 0; t < 5; ++t) {
            const float4 w = a5[t * E4 + i];
            acc[4 + t] += xv.x * w.x + xv.y * w.y + xv.z * w.z + xv.w * w.w;
        }
        {
            const float4 w = c5[i];
            acc[9] += xv.x * w.x + xv.y * w.y + xv.z * w.z + xv.w * w.w;
        }
#pragma unroll
        for (int t = 0; t < 7; ++t) {
            const float4 w = a7[t * E4 + i];
            acc[10 + t] += xv.x * w.x + xv.y * w.y + xv.z * w.z + xv.w * w.w;
        }
        {
            const float4 w = c7[i];
            acc[17] += xv.x * w.x + xv.y * w.y + xv.z * w.z + xv.w * w.w;
        }
    }

#pragma unroll
    for (int j = 0; j < NJ; ++j) dots[(size_t)j * NROWS + r] = acc[j];
}

// ---------------------------------------------------------------------------
// Phase 2: combine neighbor taps, apply sigmoid-gate + tanh projection.
// pre_k[b,l] = sum_{t=0..k-1} dots_k_tap_t[b, l + t - (k-1)/2]   (zero pad in l)
// out_k[b,l] = tanh( sigmoid(pre_k + ab_k) * (x[b,l]·cw_k) + cb_k )
// ---------------------------------------------------------------------------
__global__ __launch_bounds__(256) void combine_kernel(
    const float* __restrict__ dots,
    const float* __restrict__ ab3, const float* __restrict__ cb3,
    const float* __restrict__ ab5, const float* __restrict__ cb5,
    const float* __restrict__ ab7, const float* __restrict__ cb7,
    float* __restrict__ out)
{
    const int r = blockIdx.x * blockDim.x + threadIdx.x;
    if (r >= NROWS) return;
    const int l = r % LL;

    float pre3 = 0.0f, pre5 = 0.0f, pre7 = 0.0f;

#pragma unroll
    for (int t = 0; t < 3; ++t) {
        const int lo = l + t - 1;
        if (lo >= 0 && lo < LL) pre3 += dots[(size_t)t * NROWS + (r + t - 1)];
    }
#pragma unroll
    for (int t = 0; t < 5; ++t) {
        const int lo = l + t - 2;
        if (lo >= 0 && lo < LL) pre5 += dots[(size_t)(4 + t) * NROWS + (r + t - 2)];
    }
#pragma unroll
    for (int t = 0; t < 7; ++t) {
        const int lo = l + t - 3;
        if (lo >= 0 && lo < LL) pre7 += dots[(size_t)(10 + t) * NROWS + (r + t - 3)];
    }

    const float c3v = dots[(size_t)3 * NROWS + r];
    const float c5v = dots[(size_t)9 * NROWS + r];
    const float c7v = dots[(size_t)17 * NROWS + r];

    const float s3 = 1.0f / (1.0f + expf(-(pre3 + ab3[0])));
    const float s5 = 1.0f / (1.0f + expf(-(pre5 + ab5[0])));
    const float s7 = 1.0f / (1.0f + expf(-(pre7 + ab7[0])));

    out[r]              = tanhf(s3 * c3v + cb3[0]);
    out[NROWS + r]      = tanhf(s5 * c5v + cb5[0]);
    out[2 * NROWS + r]  = tanhf(s7 * c7v + cb7[0]);
}

extern "C" void kernel_launch(void* const* d_in, const int* in_sizes, int n_in,
                              void* d_out, int out_size, void* d_ws, size_t ws_size,
                              hipStream_t stream) {
    const float* x   = (const float*)d_in[0];
    const float* aw3 = (const float*)d_in[1];
    const float* ab3 = (const float*)d_in[2];
    const float* cw3 = (const float*)d_in[3];
    const float* cb3 = (const float*)d_in[4];
    const float* aw5 = (const float*)d_in[5];
    const float* ab5 = (const float*)d_in[6];
    const float* cw5 = (const float*)d_in[7];
    const float* cb5 = (const float*)d_in[8];
    const float* aw7 = (const float*)d_in[9];
    const float* ab7 = (const float*)d_in[10];
    const float* cw7 = (const float*)d_in[11];
    const float* cb7 = (const float*)d_in[12];

    float* dots = (float*)d_ws;   // needs 18 * 128000 * 4 = 9.216 MB
    float* out  = (float*)d_out;  // 3 * 128000 floats: [out3 | out5 | out7]

    const int threads = 256;
    const int blocks  = (NROWS + threads - 1) / threads;  // 500

    dots_kernel<<<blocks, threads, 0, stream>>>(x, aw3, cw3, aw5, cw5, aw7, cw7, dots);
    combine_kernel<<<blocks, threads, 0, stream>>>(dots, ab3, cb3, ab5, cb5, ab7, cb7, out);
}

// Round 2
// 325.524 us; speedup vs baseline: 1.0226x; 1.0226x over previous
//
#include <hip/hip_runtime.h>
#include <math.h>

#define BB 256
#define LL 500
#define EE 300
#define NROWS (BB * LL)      // 128000
#define NJ 18                // 3 (aw3) + 1 (cw3) + 5 (aw5) + 1 (cw5) + 7 (aw7) + 1 (cw7)

__device__ __forceinline__ float dot4(float4 a, float4 b) {
    return a.x * b.x + a.y * b.y + a.z * b.z + a.w * b.w;
}

// ---------------------------------------------------------------------------
// Phase 1: 16 lanes per row, 4 rows per wave.
// Row r = 4*wave + (lane/16). Lane j = lane%16 covers float4 chunks
// j, j+16, j+32, j+48 and (if j<11) j+64  (75 float4 = 300 floats).
// 18 dots per row reduced via 4-step shfl_xor butterfly within the 16-lane group.
// ---------------------------------------------------------------------------
__global__ __launch_bounds__(256) void dots_kernel(
    const float* __restrict__ x,
    const float* __restrict__ aw3, const float* __restrict__ cw3,
    const float* __restrict__ aw5, const float* __restrict__ cw5,
    const float* __restrict__ aw7, const float* __restrict__ cw7,
    float* __restrict__ dots)
{
    const int tid  = blockIdx.x * blockDim.x + threadIdx.x;
    const int wave = tid >> 6;           // global wave id, 0..31999
    const int lane = threadIdx.x & 63;
    const int g    = lane >> 4;          // row group within wave, 0..3
    const int j    = lane & 15;          // chunk lane within group, 0..15
    const int r    = wave * 4 + g;       // row id, always < 128000

    const float4* __restrict__ xr = (const float4*)(x + (size_t)r * EE);

    float4 xv0 = xr[j];
    float4 xv1 = xr[j + 16];
    float4 xv2 = xr[j + 32];
    float4 xv3 = xr[j + 48];

    const float* wptr[NJ] = {
        aw3, aw3 + 300, aw3 + 600, cw3,
        aw5, aw5 + 300, aw5 + 600, aw5 + 900, aw5 + 1200, cw5,
        aw7, aw7 + 300, aw7 + 600, aw7 + 900, aw7 + 1200, aw7 + 1500, aw7 + 1800, cw7
    };

    float acc[NJ];
#pragma unroll
    for (int d = 0; d < NJ; ++d) {
        const float4* __restrict__ wd = (const float4*)wptr[d];
        float s;
        s  = dot4(xv0, wd[j]);
        s += dot4(xv1, wd[j + 16]);
        s += dot4(xv2, wd[j + 32]);
        s += dot4(xv3, wd[j + 48]);
        acc[d] = s;
    }

    // tail chunk: only lanes j<11 (chunks 64..74)
    if (j < 11) {
        const float4 xv4 = xr[j + 64];
#pragma unroll
        for (int d = 0; d < NJ; ++d) {
            const float4* __restrict__ wd = (const float4*)wptr[d];
            acc[d] += dot4(xv4, wd[j + 64]);
        }
    }

    // butterfly reduce across the 16-lane group
#pragma unroll
    for (int d = 0; d < NJ; ++d) {
        float v = acc[d];
        v += __shfl_xor(v, 1, 16);
        v += __shfl_xor(v, 2, 16);
        v += __shfl_xor(v, 4, 16);
        v += __shfl_xor(v, 8, 16);
        acc[d] = v;
    }

    // lane j==0 of each group writes the 18 dots for its row.
    // For fixed d, the 4 active lanes write consecutive r -> 16B contiguous.
    if (j == 0) {
#pragma unroll
        for (int d = 0; d < NJ; ++d) dots[(size_t)d * NROWS + r] = acc[d];
    }
}

// ---------------------------------------------------------------------------
// Phase 2: combine neighbor taps, apply sigmoid-gate + tanh projection.
// ---------------------------------------------------------------------------
__global__ __launch_bounds__(256) void combine_kernel(
    const float* __restrict__ dots,
    const float* __restrict__ ab3, const float* __restrict__ cb3,
    const float* __restrict__ ab5, const float* __restrict__ cb5,
    const float* __restrict__ ab7, const float* __restrict__ cb7,
    float* __restrict__ out)
{
    const int r = blockIdx.x * blockDim.x + threadIdx.x;
    if (r >= NROWS) return;
    const int l = r % LL;

    float pre3 = 0.0f, pre5 = 0.0f, pre7 = 0.0f;

#pragma unroll
    for (int t = 0; t < 3; ++t) {
        const int lo = l + t - 1;
        if (lo >= 0 && lo < LL) pre3 += dots[(size_t)t * NROWS + (r + t - 1)];
    }
#pragma unroll
    for (int t = 0; t < 5; ++t) {
        const int lo = l + t - 2;
        if (lo >= 0 && lo < LL) pre5 += dots[(size_t)(4 + t) * NROWS + (r + t - 2)];
    }
#pragma unroll
    for (int t = 0; t < 7; ++t) {
        const int lo = l + t - 3;
        if (lo >= 0 && lo < LL) pre7 += dots[(size_t)(10 + t) * NROWS + (r + t - 3)];
    }

    const float c3v = dots[(size_t)3 * NROWS + r];
    const float c5v = dots[(size_t)9 * NROWS + r];
    const float c7v = dots[(size_t)17 * NROWS + r];

    const float s3 = 1.0f / (1.0f + expf(-(pre3 + ab3[0])));
    const float s5 = 1.0f / (1.0f + expf(-(pre5 + ab5[0])));
    const float s7 = 1.0f / (1.0f + expf(-(pre7 + ab7[0])));

    out[r]              = tanhf(s3 * c3v + cb3[0]);
    out[NROWS + r]      = tanhf(s5 * c5v + cb5[0]);
    out[2 * NROWS + r]  = tanhf(s7 * c7v + cb7[0]);
}

extern "C" void kernel_launch(void* const* d_in, const int* in_sizes, int n_in,
                              void* d_out, int out_size, void* d_ws, size_t ws_size,
                              hipStream_t stream) {
    const float* x   = (const float*)d_in[0];
    const float* aw3 = (const float*)d_in[1];
    const float* ab3 = (const float*)d_in[2];
    const float* cw3 = (const float*)d_in[3];
    const float* cb3 = (const float*)d_in[4];
    const float* aw5 = (const float*)d_in[5];
    const float* ab5 = (const float*)d_in[6];
    const float* cw5 = (const float*)d_in[7];
    const float* cb5 = (const float*)d_in[8];
    const float* aw7 = (const float*)d_in[9];
    const float* ab7 = (const float*)d_in[10];
    const float* cw7 = (const float*)d_in[11];
    const float* cb7 = (const float*)d_in[12];

    float* dots = (float*)d_ws;   // 18 * 128000 * 4 = 9.216 MB
    float* out  = (float*)d_out;  // [out3 | out5 | out7]

    // dots: 16 lanes/row, 4 rows/wave -> 128000/4 = 32000 waves -> 8000 blocks of 256
    dots_kernel<<<8000, 256, 0, stream>>>(x, aw3, cw3, aw5, cw5, aw7, cw7, dots);

    const int blocks = (NROWS + 255) / 256;  // 500
    combine_kernel<<<blocks, 256, 0, stream>>>(dots, ab3, cb3, ab5, cb5, ab7, cb7, out);
}

// Round 3
// 259.718 us; speedup vs baseline: 1.2817x; 1.2534x over previous
//
#include <hip/hip_runtime.h>
#include <math.h>

#define BB 256
#define LL 500
#define EE 300
#define NROWS (BB * LL)      // 128000
#define NJ 18                // 3 (aw3) + 1 (cw3) + 5 (aw5) + 1 (cw5) + 7 (aw7) + 1 (cw7)

// ---------------------------------------------------------------------------
// Phase 1: 16 lanes per row-group, 4 rows per group, 16 rows per wave.
// Lane (g = lane/16, j = lane%16): rows r0..r0+3 with r0 = 16*wave + 4*g,
// float4 chunk positions {j, j+16, j+32, j+48, (j+64 if j<11)}.
// Each weight chunk is loaded ONCE and used for 4 rows (4x less L1 service
// than the R2 version, which was L1-latency bound at VALUBusy=22%).
// ---------------------------------------------------------------------------
__global__ __launch_bounds__(256) void dots_kernel(
    const float* __restrict__ x,
    const float* __restrict__ aw3, const float* __restrict__ cw3,
    const float* __restrict__ aw5, const float* __restrict__ cw5,
    const float* __restrict__ aw7, const float* __restrict__ cw7,
    float* __restrict__ dots)
{
    const int tid  = blockIdx.x * blockDim.x + threadIdx.x;
    const int wave = tid >> 6;           // 0..7999
    const int lane = threadIdx.x & 63;
    const int g    = lane >> 4;          // 0..3
    const int j    = lane & 15;          // 0..15
    const int r0   = wave * 16 + g * 4;  // base row of this group's 4 rows

    const float4* __restrict__ xr0 = (const float4*)(x + (size_t)(r0 + 0) * EE);
    const float4* __restrict__ xr1 = (const float4*)(x + (size_t)(r0 + 1) * EE);
    const float4* __restrict__ xr2 = (const float4*)(x + (size_t)(r0 + 2) * EE);
    const float4* __restrict__ xr3 = (const float4*)(x + (size_t)(r0 + 3) * EE);

    const float* const wptr[NJ] = {
        aw3, aw3 + 300, aw3 + 600, cw3,
        aw5, aw5 + 300, aw5 + 600, aw5 + 900, aw5 + 1200, cw5,
        aw7, aw7 + 300, aw7 + 600, aw7 + 900, aw7 + 1200, aw7 + 1500, aw7 + 1800, cw7
    };

    float acc[NJ][4];
#pragma unroll
    for (int d = 0; d < NJ; ++d)
#pragma unroll
        for (int rr = 0; rr < 4; ++rr) acc[d][rr] = 0.0f;

#define BODY(c)                                                                     \
    {                                                                               \
        const float4 x0 = xr0[(c)];                                                 \
        const float4 x1 = xr1[(c)];                                                 \
        const float4 x2 = xr2[(c)];                                                 \
        const float4 x3 = xr3[(c)];                                                 \
        _Pragma("unroll")                                                           \
        for (int d = 0; d < NJ; ++d) {                                              \
            const float4 w = ((const float4*)wptr[d])[(c)];                         \
            acc[d][0] = fmaf(x0.w, w.w, fmaf(x0.z, w.z, fmaf(x0.y, w.y, fmaf(x0.x, w.x, acc[d][0])))); \
            acc[d][1] = fmaf(x1.w, w.w, fmaf(x1.z, w.z, fmaf(x1.y, w.y, fmaf(x1.x, w.x, acc[d][1])))); \
            acc[d][2] = fmaf(x2.w, w.w, fmaf(x2.z, w.z, fmaf(x2.y, w.y, fmaf(x2.x, w.x, acc[d][2])))); \
            acc[d][3] = fmaf(x3.w, w.w, fmaf(x3.z, w.z, fmaf(x3.y, w.y, fmaf(x3.x, w.x, acc[d][3])))); \
        }                                                                           \
    }

    BODY(j)
    BODY(j + 16)
    BODY(j + 32)
    BODY(j + 48)
    if (j < 11) {
        BODY(j + 64)
    }
#undef BODY

    // butterfly reduce each (d, rr) across the 16-lane group
#pragma unroll
    for (int d = 0; d < NJ; ++d)
#pragma unroll
        for (int rr = 0; rr < 4; ++rr) {
            float v = acc[d][rr];
            v += __shfl_xor(v, 1, 16);
            v += __shfl_xor(v, 2, 16);
            v += __shfl_xor(v, 4, 16);
            v += __shfl_xor(v, 8, 16);
            acc[d][rr] = v;
        }

    // lane j == rr writes row r0+rr (compile-time register indexing, predicated)
#pragma unroll
    for (int rr = 0; rr < 4; ++rr) {
        if (j == rr) {
            const int r = r0 + rr;
#pragma unroll
            for (int d = 0; d < NJ; ++d) dots[(size_t)d * NROWS + r] = acc[d][rr];
        }
    }
}

// ---------------------------------------------------------------------------
// Phase 2: combine neighbor taps, apply sigmoid-gate + tanh projection.
// ---------------------------------------------------------------------------
__global__ __launch_bounds__(256) void combine_kernel(
    const float* __restrict__ dots,
    const float* __restrict__ ab3, const float* __restrict__ cb3,
    const float* __restrict__ ab5, const float* __restrict__ cb5,
    const float* __restrict__ ab7, const float* __restrict__ cb7,
    float* __restrict__ out)
{
    const int r = blockIdx.x * blockDim.x + threadIdx.x;
    if (r >= NROWS) return;
    const int l = r % LL;

    float pre3 = 0.0f, pre5 = 0.0f, pre7 = 0.0f;

#pragma unroll
    for (int t = 0; t < 3; ++t) {
        const int lo = l + t - 1;
        if (lo >= 0 && lo < LL) pre3 += dots[(size_t)t * NROWS + (r + t - 1)];
    }
#pragma unroll
    for (int t = 0; t < 5; ++t) {
        const int lo = l + t - 2;
        if (lo >= 0 && lo < LL) pre5 += dots[(size_t)(4 + t) * NROWS + (r + t - 2)];
    }
#pragma unroll
    for (int t = 0; t < 7; ++t) {
        const int lo = l + t - 3;
        if (lo >= 0 && lo < LL) pre7 += dots[(size_t)(10 + t) * NROWS + (r + t - 3)];
    }

    const float c3v = dots[(size_t)3 * NROWS + r];
    const float c5v = dots[(size_t)9 * NROWS + r];
    const float c7v = dots[(size_t)17 * NROWS + r];

    const float s3 = 1.0f / (1.0f + expf(-(pre3 + ab3[0])));
    const float s5 = 1.0f / (1.0f + expf(-(pre5 + ab5[0])));
    const float s7 = 1.0f / (1.0f + expf(-(pre7 + ab7[0])));

    out[r]              = tanhf(s3 * c3v + cb3[0]);
    out[NROWS + r]      = tanhf(s5 * c5v + cb5[0]);
    out[2 * NROWS + r]  = tanhf(s7 * c7v + cb7[0]);
}

extern "C" void kernel_launch(void* const* d_in, const int* in_sizes, int n_in,
                              void* d_out, int out_size, void* d_ws, size_t ws_size,
                              hipStream_t stream) {
    const float* x   = (const float*)d_in[0];
    const float* aw3 = (const float*)d_in[1];
    const float* ab3 = (const float*)d_in[2];
    const float* cw3 = (const float*)d_in[3];
    const float* cb3 = (const float*)d_in[4];
    const float* aw5 = (const float*)d_in[5];
    const float* ab5 = (const float*)d_in[6];
    const float* cw5 = (const float*)d_in[7];
    const float* cb5 = (const float*)d_in[8];
    const float* aw7 = (const float*)d_in[9];
    const float* ab7 = (const float*)d_in[10];
    const float* cw7 = (const float*)d_in[11];
    const float* cb7 = (const float*)d_in[12];

    float* dots = (float*)d_ws;   // 18 * 128000 * 4 = 9.216 MB
    float* out  = (float*)d_out;  // [out3 | out5 | out7]

    // 16 rows per wave -> 128000/16 = 8000 waves -> 2000 blocks of 256
    dots_kernel<<<2000, 256, 0, stream>>>(x, aw3, cw3, aw5, cw5, aw7, cw7, dots);

    const int blocks = (NROWS + 255) / 256;  // 500
    combine_kernel<<<blocks, 256, 0, stream>>>(dots, ab3, cb3, ab5, cb5, ab7, cb7, out);
}